// Round 1
// 296.109 us; speedup vs baseline: 1.0152x; 1.0152x over previous
//
#include <hip/hip_runtime.h>
#include <hip/hip_bf16.h>
#include <stdint.h>
#include <string.h>

// Problem constants (fixed by the reference)
#define NUM_CHIPS 4
#define N_EXPERTS 32
#define TOP_K 4
#define SEQ 1024
#define HIDDEN 2048
#define MAX_TOK 1024
#define META_LEN 8
#define NPC (SEQ * TOP_K)            // 4096 assignments per chip
#define NTOT (NUM_CHIPS * NPC)       // 16384 assignments total
#define ROWS (N_EXPERTS * MAX_TOK)   // 32768 output rows
#define BUF_ELEMS ((size_t)ROWS * HIDDEN)           // 67,108,864
#define META_OFF BUF_ELEMS
#define CNT_OFF (BUF_ELEMS + (size_t)ROWS * META_LEN)

// Workspace layout (ints)
#define WS_RANK 0                    // [NTOT]   within-chip stable rank
#define WS_CNT  (NTOT)               // [4][32]  per-chip per-expert counts

#define OCC_BLOCKS (NUM_CHIPS * SEQ) // 4096 token-driven blocks
#define EMPTY_BLOCKS (ROWS / 4)      // 8192 zero-fill blocks (4 rows each)

typedef float vfloat4 __attribute__((ext_vector_type(4)));

// ---------------------------------------------------------------------------
// rank_kernel: one block per chip, 1024 threads. All 4096 expert ids loaded
// into registers up-front; 4 serial chunk iterations of ballot-rank +
// 16-wave LDS scan. Produces within-chip stable rank per assignment and the
// per-chip per-expert counts. ~4 us. (unchanged)
// ---------------------------------------------------------------------------
__global__ __launch_bounds__(1024) void rank_kernel(const int* __restrict__ idx,
                                                    int* __restrict__ ws) {
    __shared__ int run_base[N_EXPERTS];       // running per-expert count
    __shared__ int wave_cnt[16][N_EXPERTS];   // per-wave group sizes in chunk
    __shared__ int wave_base[16][N_EXPERTS];  // exclusive base per wave

    const int c = blockIdx.x;
    const int t = threadIdx.x;
    const int lane = t & 63;
    const int w = t >> 6;

    int e[4];
#pragma unroll
    for (int q = 0; q < 4; ++q) e[q] = idx[c * NPC + q * 1024 + t];

    if (t < N_EXPERTS) run_base[t] = 0;
    __syncthreads();

#pragma unroll
    for (int q = 0; q < 4; ++q) {
        if (t < 16 * N_EXPERTS) ((int*)wave_cnt)[t] = 0;
        __syncthreads();

        // mask of lanes in this wave routed to the same expert
        uint64_t m = ~0ull;
#pragma unroll
        for (int b = 0; b < 5; ++b) {
            uint64_t bb = __ballot((e[q] >> b) & 1);
            m &= ((e[q] >> b) & 1) ? bb : ~bb;
        }
        const int rk = __popcll(m & ((1ull << lane) - 1ull));  // stable in-wave rank
        if (rk == 0) wave_cnt[w][e[q]] = __popcll(m);          // group leader
        __syncthreads();

        // cross-wave exclusive scan per expert, update running base
        if (t < N_EXPERTS) {
            int s = run_base[t];
#pragma unroll
            for (int ww = 0; ww < 16; ++ww) {
                wave_base[ww][t] = s;
                s += wave_cnt[ww][t];
            }
            run_base[t] = s;
        }
        __syncthreads();

        ws[WS_RANK + c * NPC + q * 1024 + t] = wave_base[w][e[q]] + rk;
        // next writes to wave_base occur only after two more __syncthreads().
    }
    __syncthreads();
    if (t < N_EXPERTS) ws[WS_CNT + c * N_EXPERTS + t] = run_base[t];
}

// ---------------------------------------------------------------------------
// scatter_all: single fused dispatch.
//   blocks [0, OCC_BLOCKS)            : token-driven scatter (one (chip,token)
//                                       per block; reads the 8 KB x row once,
//                                       writes its K=4 destination rows)
//   blocks [OCC_BLOCKS, +EMPTY_BLOCKS): zero-fill of unoccupied rows
//                                       (4 rows per block, pure write stream)
// The two roles write disjoint rows (slot < tot vs slot >= tot), so no
// ordering between them is needed — fusing removes one kernel-boundary drain
// and overlaps occ's read latency with empty's pure write stream.
// All stores are PLAIN (L2-allocating) stores: the rocclr poison fill proves
// this buffer sustains 6.3+ TB/s with plain stores; nontemporal stores were
// the prime suspect for the <2.3 TB/s effective scatter bandwidth.
// ---------------------------------------------------------------------------
__global__ __launch_bounds__(256) void scatter_all(const float* __restrict__ x,
                                                   const float* __restrict__ wts,
                                                   const int* __restrict__ idx,
                                                   const int* __restrict__ ws,
                                                   float* __restrict__ out) {
    __shared__ int cnt_s[NUM_CHIPS * N_EXPERTS];
    const int t = threadIdx.x;
    const int b = blockIdx.x;

    if (b < OCC_BLOCKS) {
        // ---------------- token-driven scatter ----------------
        const int c = b >> 10;                 // chip
        const int tk = b & (SEQ - 1);          // token

        if (t < NUM_CHIPS * N_EXPERTS) cnt_s[t] = ws[WS_CNT + t];

        // this token's hidden vector (read once)
        const vfloat4* src = (const vfloat4*)(x + ((size_t)c * SEQ + tk) * HIDDEN);
        vfloat4 v0 = src[t];
        vfloat4 v1 = src[t + 256];

        int e[TOP_K], rk[TOP_K];
#pragma unroll
        for (int k = 0; k < TOP_K; ++k) {
            e[k] = idx[c * NPC + tk * TOP_K + k];
            rk[k] = ws[WS_RANK + c * NPC + tk * TOP_K + k];
        }
        __syncthreads();

#pragma unroll
        for (int k = 0; k < TOP_K; ++k) {
            // cross-chip exclusive offset (serialized chip order, as reference)
            int off = 0;
            for (int cc = 0; cc < c; ++cc) off += cnt_s[cc * N_EXPERTS + e[k]];
            const int row = e[k] * MAX_TOK + off + rk[k];

            vfloat4* dst = (vfloat4*)(out + (size_t)row * HIDDEN);
            dst[t] = v0;
            dst[t + 256] = v1;

            if (t < META_LEN) {
                float mv = 0.0f;
                if (t == 0) mv = (float)c;
                else if (t == 1) mv = (float)tk;
                else if (t == 2) mv = (float)k;
                else if (t == 3) mv = (float)e[k];
                else if (t == 4) {
                    // bf16 bits of the routing weight, RNE (matches jax astype)
                    float wv = wts[c * NPC + tk * TOP_K + k];
                    uint32_t ub;
                    memcpy(&ub, &wv, 4);
                    uint32_t lsb = (ub >> 16) & 1u;
                    uint32_t bits = (ub + 0x7FFFu + lsb) >> 16;
                    mv = (float)(int)(short)(uint16_t)bits;  // sign-extend int16
                }
                out[META_OFF + (size_t)row * META_LEN + t] = mv;
            }
        }
    } else {
        // ---------------- zero-fill of unoccupied rows ----------------
        const int row0 = (b - OCC_BLOCKS) * 4;
        const int e = row0 >> 10;
        const int slot0 = row0 & (MAX_TOK - 1);

        const int tot = ws[WS_CNT + e] + ws[WS_CNT + N_EXPERTS + e] +
                        ws[WS_CNT + 2 * N_EXPERTS + e] + ws[WS_CNT + 3 * N_EXPERTS + e];

        if (b == OCC_BLOCKS && t < N_EXPERTS) {
            int s = ws[WS_CNT + t] + ws[WS_CNT + N_EXPERTS + t] +
                    ws[WS_CNT + 2 * N_EXPERTS + t] + ws[WS_CNT + 3 * N_EXPERTS + t];
            out[CNT_OFF + t] = (float)s;
        }

        if (slot0 + 3 < tot) return;              // fully occupied group: nothing to do

        const vfloat4 z = (vfloat4)(0.f);
#pragma unroll
        for (int r = 0; r < 4; ++r) {
            if (slot0 + r < tot) continue;        // occupied row handled by occ role
            vfloat4* dst = (vfloat4*)(out + (size_t)(row0 + r) * HIDDEN);
            dst[t] = z;
            dst[t + 256] = z;
            if (t < META_LEN)
                out[META_OFF + (size_t)(row0 + r) * META_LEN + t] = -1.0f;
        }
    }
}

extern "C" void kernel_launch(void* const* d_in, const int* in_sizes, int n_in,
                              void* d_out, int out_size, void* d_ws, size_t ws_size,
                              hipStream_t stream) {
    const float* x   = (const float*)d_in[0];   // [4,1024,2048] f32
    const float* wts = (const float*)d_in[1];   // [4,1024,4]    f32
    const int*   idx = (const int*)d_in[2];     // [4,1024,4]    i32
    float* out = (float*)d_out;
    int* ws = (int*)d_ws;

    rank_kernel<<<NUM_CHIPS, 1024, 0, stream>>>(idx, ws);
    scatter_all<<<OCC_BLOCKS + EMPTY_BLOCKS, 256, 0, stream>>>(x, wts, idx, ws, out);
}